// Round 1
// baseline (153.383 us; speedup 1.0000x reference)
//
#include <hip/hip_runtime.h>

// Problem constants (from reference): B=8, T=32768, F_IN=64, N=64, F=64, HID=32
#define BB   8
#define TT   32768
#define FIN  64
#define HIDN 32
#define NST  64
#define FFD  64
#define WWIN 256        // FIR window: A^256 = exp(-256*softplus(-0.7)) ~ 1e-45 -> exact in fp32
#define TILE 1024       // conv outputs per block

// Workspace layout (floats):
//   [0..31]    wu_h = W2 @ Wu
//   [32..63]   wd_h = W2 @ D
//   [64]       cu = b2.Wu          [65] cd = b2.D + b_y
//   [128..383] K[j] = sum_n C[n]*P[n]*A[n]^j
//   [512..512+B*T) u[b,t]
// total = 512 + 262144 floats ~= 1.003 MB

__global__ __launch_bounds__(256) void setup_kernel(
    const float* __restrict__ W2, const float* __restrict__ b2,
    const float* __restrict__ Lraw, const float* __restrict__ P,
    const float* __restrict__ Wu, const float* __restrict__ C,
    const float* __restrict__ Dv, const float* __restrict__ b_y,
    float* __restrict__ ws)
{
    int tid = threadIdx.x;
    if (tid < HIDN) {
        float su = 0.f, sd = 0.f;
        for (int f = 0; f < FFD; ++f) {
            float w2 = W2[tid * FFD + f];
            su += w2 * Wu[f];
            sd += w2 * Dv[f];
        }
        ws[tid]      = su;
        ws[32 + tid] = sd;
    }
    if (tid == 64) {
        float cu = 0.f, cd = 0.f;
        for (int f = 0; f < FFD; ++f) { cu += b2[f] * Wu[f]; cd += b2[f] * Dv[f]; }
        ws[64] = cu;
        ws[65] = cd + b_y[0];
    }
    if (tid < WWIN) {
        // K[j] = sum_n C*P * exp(-j * softplus(Lraw[n]))
        float acc = 0.f;
        float jf = (float)tid;
        for (int n = 0; n < NST; ++n) {
            float raw = Lraw[n];
            float sp  = fmaxf(raw, 0.f) + log1pf(expf(-fabsf(raw)));  // stable softplus
            acc += C[n] * P[n] * __expf(-sp * jf);
        }
        ws[128 + tid] = acc;
    }
}

// One thread per timestep: h = relu(x@W1 + b1); u = h.wu_h + cu; yd = h.wd_h + cd
__global__ __launch_bounds__(256) void mlp_kernel(
    const float* __restrict__ x, const float* __restrict__ W1,
    const float* __restrict__ b1, const float* __restrict__ ws,
    float* __restrict__ u, float* __restrict__ yd)
{
    __shared__ __align__(16) float W1s[FIN * HIDN];  // [i][h], row-major like input
    __shared__ __align__(16) float b1s[HIDN];
    __shared__ __align__(16) float wus[HIDN];
    __shared__ __align__(16) float wds[HIDN];
    __shared__ float cucd[2];

    int tid = threadIdx.x;
    for (int s = tid; s < FIN * HIDN; s += 256) W1s[s] = W1[s];
    if (tid < HIDN) {
        b1s[tid] = b1[tid];
        wus[tid] = ws[tid];
        wds[tid] = ws[32 + tid];
    }
    if (tid == 64) { cucd[0] = ws[64]; cucd[1] = ws[65]; }
    __syncthreads();

    int idx = blockIdx.x * 256 + tid;            // grid=1024 covers B*T exactly
    const float4* xp = (const float4*)(x + (size_t)idx * FIN);

    float4 acc[8];
#pragma unroll
    for (int hb = 0; hb < 8; ++hb) acc[hb] = *(const float4*)&b1s[hb * 4];

#pragma unroll 4
    for (int i4 = 0; i4 < 16; ++i4) {
        float4 xv = xp[i4];
        float xs[4] = {xv.x, xv.y, xv.z, xv.w};
#pragma unroll
        for (int k = 0; k < 4; ++k) {
            float xi = xs[k];
            int i = i4 * 4 + k;
#pragma unroll
            for (int hb = 0; hb < 8; ++hb) {
                float4 w = *(const float4*)&W1s[i * HIDN + hb * 4];  // wave-uniform -> LDS broadcast
                acc[hb].x += xi * w.x;
                acc[hb].y += xi * w.y;
                acc[hb].z += xi * w.z;
                acc[hb].w += xi * w.w;
            }
        }
    }

    float ut = cucd[0], yt = cucd[1];
#pragma unroll
    for (int hb = 0; hb < 8; ++hb) {
        float4 h = acc[hb];
        h.x = fmaxf(h.x, 0.f); h.y = fmaxf(h.y, 0.f);
        h.z = fmaxf(h.z, 0.f); h.w = fmaxf(h.w, 0.f);
        float4 a = *(const float4*)&wus[hb * 4];
        float4 d = *(const float4*)&wds[hb * 4];
        ut += h.x * a.x + h.y * a.y + h.z * a.z + h.w * a.w;
        yt += h.x * d.x + h.y * d.y + h.z * d.z + h.w * d.w;
    }
    u[idx]  = ut;
    yd[idx] = yt;   // yd written straight into d_out; conv kernel adds the state term
}

// Causal FIR: y[b,t] = yd[b,t] + sum_{j<WWIN} K[j]*u[b,t-j]
// Each block: one batch, TILE contiguous timesteps; each thread 4 outputs.
__global__ __launch_bounds__(256) void conv_kernel(
    const float* __restrict__ u, const float* __restrict__ K,
    float* __restrict__ y)
{
    __shared__ __align__(16) float us[WWIN + TILE];   // 1280 floats
    __shared__ __align__(16) float Ks[WWIN];

    int tid = threadIdx.x;
    const int blocksPerSeq = TT / TILE;               // 32
    int b  = blockIdx.x / blocksPerSeq;
    int t0 = (blockIdx.x % blocksPerSeq) * TILE;
    const float* ub = u + (size_t)b * TT;

    for (int s = tid; s < WWIN + TILE; s += 256) {
        int gt = t0 - WWIN + s;
        us[s] = (gt >= 0) ? ub[gt] : 0.f;             // zero-pad before sequence start
    }
    if (tid < WWIN) Ks[tid] = K[tid];
    __syncthreads();

    int base = WWIN + tid * 4;                        // outputs at t0 + 4*tid + {0..3}
    size_t oidx = (size_t)b * TT + t0 + tid * 4;
    float4 yv = *(const float4*)&y[oidx];             // yd from mlp_kernel
    float a0 = yv.x, a1 = yv.y, a2 = yv.z, a3 = yv.w;

#pragma unroll 8
    for (int j = 0; j < WWIN; j += 4) {
        float4 kk = *(const float4*)&Ks[j];
        float4 ua = *(const float4*)&us[base - j - 4];  // indices base-j-4 .. base-j-1
        float4 ux = *(const float4*)&us[base - j];      // indices base-j   .. base-j+3
        // acc[k] += kk[jj] * us[base + k - j - jj]
        a0 += kk.x * ux.x + kk.y * ua.w + kk.z * ua.z + kk.w * ua.y;
        a1 += kk.x * ux.y + kk.y * ux.x + kk.z * ua.w + kk.w * ua.z;
        a2 += kk.x * ux.z + kk.y * ux.y + kk.z * ux.x + kk.w * ua.w;
        a3 += kk.x * ux.w + kk.y * ux.z + kk.z * ux.y + kk.w * ux.x;
    }
    *(float4*)&y[oidx] = make_float4(a0, a1, a2, a3);
}

extern "C" void kernel_launch(void* const* d_in, const int* in_sizes, int n_in,
                              void* d_out, int out_size, void* d_ws, size_t ws_size,
                              hipStream_t stream)
{
    const float* x    = (const float*)d_in[0];
    const float* W1   = (const float*)d_in[1];
    const float* b1   = (const float*)d_in[2];
    const float* W2   = (const float*)d_in[3];
    const float* b2   = (const float*)d_in[4];
    const float* Lraw = (const float*)d_in[5];
    const float* P    = (const float*)d_in[6];
    const float* Wu   = (const float*)d_in[7];
    const float* C    = (const float*)d_in[8];
    const float* Dv   = (const float*)d_in[9];
    const float* b_y  = (const float*)d_in[10];

    float* ws = (float*)d_ws;
    float* u  = ws + 512;
    float* y  = (float*)d_out;

    setup_kernel<<<1, 256, 0, stream>>>(W2, b2, Lraw, P, Wu, C, Dv, b_y, ws);
    mlp_kernel<<<(BB * TT) / 256, 256, 0, stream>>>(x, W1, b1, ws, u, y);
    conv_kernel<<<(BB * TT) / TILE, 256, 0, stream>>>(u, ws + 128, y);
}

// Round 2
// 140.680 us; speedup vs baseline: 1.0903x; 1.0903x over previous
//
#include <hip/hip_runtime.h>

// Problem constants: B=8, T=32768, F_IN=64, N=64, F=64, HID=32
#define BB   8
#define TT   32768
#define FIN  64
#define HIDN 32
#define NST  64
#define FFD  64
#define WWIN 256        // FIR window: A^256 = exp(-256*softplus(-0.7)) ~ 1e-45 -> exact in fp32
#define TILE 1024       // conv outputs per block

// Workspace layout (floats):
//   [0..31]     wu_h = W2 @ Wu
//   [32..63]    wd_h = W2 @ D
//   [64]        cu = b2.Wu          [65] cd = b2.D + b_y
//   [128..383]  K[j] = sum_n C[n]*P[n]*A[n]^j
//   [512..1535] W1 bf16 B-fragments: 4 frags x 64 lanes x 8 bf16 (uint4 each)
//   [2048..2048+B*T) u[b,t]

typedef __attribute__((ext_vector_type(8))) short short8;
typedef __attribute__((ext_vector_type(4))) float f32x4;

static __device__ __forceinline__ unsigned short f2bf(float f) {
    unsigned int u = __builtin_bit_cast(unsigned int, f);
    unsigned int lsb = (u >> 16) & 1u;
    u += 0x7fffu + lsb;                 // round-to-nearest-even
    return (unsigned short)(u >> 16);
}

__global__ __launch_bounds__(256) void setup_kernel(
    const float* __restrict__ W1, const float* __restrict__ W2,
    const float* __restrict__ b2, const float* __restrict__ Lraw,
    const float* __restrict__ P, const float* __restrict__ Wu,
    const float* __restrict__ C, const float* __restrict__ Dv,
    const float* __restrict__ b_y, float* __restrict__ ws)
{
    int tid = threadIdx.x;
    if (tid < HIDN) {
        float su = 0.f, sd = 0.f;
        for (int f = 0; f < FFD; ++f) {
            float w2 = W2[tid * FFD + f];
            su += w2 * Wu[f];
            sd += w2 * Dv[f];
        }
        ws[tid]      = su;
        ws[32 + tid] = sd;
    }
    if (tid == 64) {
        float cu = 0.f, cd = 0.f;
        for (int f = 0; f < FFD; ++f) { cu += b2[f] * Wu[f]; cd += b2[f] * Dv[f]; }
        ws[64] = cu;
        ws[65] = cd + b_y[0];
    }
    if (tid < WWIN) {
        float acc = 0.f;
        float jf = (float)tid;
        for (int n = 0; n < NST; ++n) {
            float raw = Lraw[n];
            float sp  = fmaxf(raw, 0.f) + log1pf(expf(-fabsf(raw)));  // stable softplus
            acc += C[n] * P[n] * __expf(-sp * jf);
        }
        ws[128 + tid] = acc;
    }
    // W1 -> bf16 MFMA B-fragments. frag f = khalf + 2*ntile.
    // B[k][n] element held by lane: n = (lane&15) + 16*ntile, k = khalf*32 + (lane>>4)*8 + j
    {
        int f    = tid >> 6;
        int lane = tid & 63;
        int khalf = f & 1, ntile = f >> 1;
        int quad = lane >> 4;
        int nn   = (lane & 15) + ntile * 16;
        unsigned short h8[8];
#pragma unroll
        for (int j = 0; j < 8; ++j) {
            int k = khalf * 32 + quad * 8 + j;
            h8[j] = f2bf(W1[k * HIDN + nn]);
        }
        unsigned int w0 = (unsigned int)h8[0] | ((unsigned int)h8[1] << 16);
        unsigned int w1 = (unsigned int)h8[2] | ((unsigned int)h8[3] << 16);
        unsigned int w2 = (unsigned int)h8[4] | ((unsigned int)h8[5] << 16);
        unsigned int w3 = (unsigned int)h8[6] | ((unsigned int)h8[7] << 16);
        ((uint4*)(ws + 512))[tid] = make_uint4(w0, w1, w2, w3);
    }
}

// One wave per 16 timesteps. D[t][n] = x[t][:] @ W1[:][n] via 4 MFMAs, no LDS.
__global__ __launch_bounds__(256) void mlp_kernel(
    const float* __restrict__ x, const float* __restrict__ b1,
    const float* __restrict__ ws, float* __restrict__ u,
    float* __restrict__ yd)
{
    int lane = threadIdx.x & 63;
    int wid  = threadIdx.x >> 6;
    int tile = blockIdx.x * 4 + wid;          // 16384 tiles total
    int t0   = tile * 16;
    int m    = lane & 15;
    int quad = lane >> 4;

    // W1 fragments (wave-shared values, one 16B load each from L2/L3)
    const short8* frp = (const short8*)(ws + 512);
    short8 bk0n0 = frp[0 * 64 + lane];
    short8 bk1n0 = frp[1 * 64 + lane];
    short8 bk0n1 = frp[2 * 64 + lane];
    short8 bk1n1 = frp[3 * 64 + lane];

    // A fragments: lane holds x[t0+m][quad*8 + j] (khalf0) and +32 (khalf1)
    const float* xr = x + (size_t)(t0 + m) * FIN + quad * 8;
    float4 xa0 = *(const float4*)(xr);
    float4 xa1 = *(const float4*)(xr + 4);
    float4 xb0 = *(const float4*)(xr + 32);
    float4 xb1 = *(const float4*)(xr + 36);

    short8 a0, a1;
    a0[0] = (short)f2bf(xa0.x); a0[1] = (short)f2bf(xa0.y);
    a0[2] = (short)f2bf(xa0.z); a0[3] = (short)f2bf(xa0.w);
    a0[4] = (short)f2bf(xa1.x); a0[5] = (short)f2bf(xa1.y);
    a0[6] = (short)f2bf(xa1.z); a0[7] = (short)f2bf(xa1.w);
    a1[0] = (short)f2bf(xb0.x); a1[1] = (short)f2bf(xb0.y);
    a1[2] = (short)f2bf(xb0.z); a1[3] = (short)f2bf(xb0.w);
    a1[4] = (short)f2bf(xb1.x); a1[5] = (short)f2bf(xb1.y);
    a1[6] = (short)f2bf(xb1.z); a1[7] = (short)f2bf(xb1.w);

    f32x4 acc0 = {0.f, 0.f, 0.f, 0.f};
    f32x4 acc1 = {0.f, 0.f, 0.f, 0.f};
    acc0 = __builtin_amdgcn_mfma_f32_16x16x32_bf16(a0, bk0n0, acc0, 0, 0, 0);
    acc0 = __builtin_amdgcn_mfma_f32_16x16x32_bf16(a1, bk1n0, acc0, 0, 0, 0);
    acc1 = __builtin_amdgcn_mfma_f32_16x16x32_bf16(a0, bk0n1, acc1, 0, 0, 0);
    acc1 = __builtin_amdgcn_mfma_f32_16x16x32_bf16(a1, bk1n1, acc1, 0, 0, 0);

    // Epilogue. C/D layout: col(n) = lane&15, row(t) = quad*4 + reg  [HW-verified]
    float b1n0 = b1[m];
    float b1n1 = b1[16 + m];
    float wu0  = ws[m],      wu1 = ws[16 + m];
    float wd0  = ws[32 + m], wd1 = ws[48 + m];
    float cu   = ws[64],     cd  = ws[65];

    float ut[4], yt[4];
#pragma unroll
    for (int r = 0; r < 4; ++r) {
        float h0 = fmaxf(acc0[r] + b1n0, 0.f);
        float h1 = fmaxf(acc1[r] + b1n1, 0.f);
        ut[r] = h0 * wu0 + h1 * wu1;
        yt[r] = h0 * wd0 + h1 * wd1;
    }
    // reduce over n (16 lanes within each quad-group)
#pragma unroll
    for (int mask = 1; mask <= 8; mask <<= 1) {
#pragma unroll
        for (int r = 0; r < 4; ++r) {
            ut[r] += __shfl_xor(ut[r], mask);
            yt[r] += __shfl_xor(yt[r], mask);
        }
    }
    if (m == 0) {
        int row = t0 + quad * 4;
        *(float4*)&u[row]  = make_float4(ut[0] + cu, ut[1] + cu, ut[2] + cu, ut[3] + cu);
        *(float4*)&yd[row] = make_float4(yt[0] + cd, yt[1] + cd, yt[2] + cd, yt[3] + cd);
    }
}

// Causal FIR: y[b,t] = yd[b,t] + sum_{j<WWIN} K[j]*u[b,t-j]
__global__ __launch_bounds__(256) void conv_kernel(
    const float* __restrict__ u, const float* __restrict__ K,
    float* __restrict__ y)
{
    __shared__ __align__(16) float us[WWIN + TILE];
    __shared__ __align__(16) float Ks[WWIN];

    int tid = threadIdx.x;
    const int blocksPerSeq = TT / TILE;               // 32
    int b  = blockIdx.x / blocksPerSeq;
    int t0 = (blockIdx.x % blocksPerSeq) * TILE;
    const float* ub = u + (size_t)b * TT;

    for (int s = tid; s < WWIN + TILE; s += 256) {
        int gt = t0 - WWIN + s;
        us[s] = (gt >= 0) ? ub[gt] : 0.f;
    }
    if (tid < WWIN) Ks[tid] = K[tid];
    __syncthreads();

    int base = WWIN + tid * 4;
    size_t oidx = (size_t)b * TT + t0 + tid * 4;
    float4 yv = *(const float4*)&y[oidx];             // yd from mlp_kernel
    float a0 = yv.x, a1 = yv.y, a2 = yv.z, a3 = yv.w;

#pragma unroll 8
    for (int j = 0; j < WWIN; j += 4) {
        float4 kk = *(const float4*)&Ks[j];
        float4 ua = *(const float4*)&us[base - j - 4];
        float4 ux = *(const float4*)&us[base - j];
        a0 += kk.x * ux.x + kk.y * ua.w + kk.z * ua.z + kk.w * ua.y;
        a1 += kk.x * ux.y + kk.y * ux.x + kk.z * ua.w + kk.w * ua.z;
        a2 += kk.x * ux.z + kk.y * ux.y + kk.z * ux.x + kk.w * ua.w;
        a3 += kk.x * ux.w + kk.y * ux.z + kk.z * ux.y + kk.w * ux.x;
    }
    *(float4*)&y[oidx] = make_float4(a0, a1, a2, a3);
}

extern "C" void kernel_launch(void* const* d_in, const int* in_sizes, int n_in,
                              void* d_out, int out_size, void* d_ws, size_t ws_size,
                              hipStream_t stream)
{
    const float* x    = (const float*)d_in[0];
    const float* W1   = (const float*)d_in[1];
    const float* b1   = (const float*)d_in[2];
    const float* W2   = (const float*)d_in[3];
    const float* b2   = (const float*)d_in[4];
    const float* Lraw = (const float*)d_in[5];
    const float* P    = (const float*)d_in[6];
    const float* Wu   = (const float*)d_in[7];
    const float* C    = (const float*)d_in[8];
    const float* Dv   = (const float*)d_in[9];
    const float* b_y  = (const float*)d_in[10];

    float* ws = (float*)d_ws;
    float* u  = ws + 2048;
    float* y  = (float*)d_out;

    setup_kernel<<<1, 256, 0, stream>>>(W1, W2, b2, Lraw, P, Wu, C, Dv, b_y, ws);
    mlp_kernel<<<(BB * TT / 16) / 4, 256, 0, stream>>>(x, b1, ws, u, y);
    conv_kernel<<<(BB * TT) / TILE, 256, 0, stream>>>(u, ws + 128, y);
}

// Round 3
// 123.447 us; speedup vs baseline: 1.2425x; 1.1396x over previous
//
#include <hip/hip_runtime.h>

// Problem constants: B=8, T=32768, F_IN=64, N=64, F=64, HID=32
#define BB   8
#define TT   32768
#define FIN  64
#define HIDN 32
#define NST  64
#define FFD  64
#define WWIN 256        // FIR window: A^256 ~ 1e-45 -> exact truncation in fp32
#define TILE 1024       // conv outputs per block
#define TPW  4          // MFMA tiles (of 16 timesteps) per wave in mlp

typedef __attribute__((ext_vector_type(8))) short short8;
typedef __attribute__((ext_vector_type(4))) float f32x4;

static __device__ __forceinline__ unsigned short f2bf(float f) {
    unsigned int u = __builtin_bit_cast(unsigned int, f);
    unsigned int lsb = (u >> 16) & 1u;
    u += 0x7fffu + lsb;                 // round-to-nearest-even
    return (unsigned short)(u >> 16);
}

static __device__ __forceinline__ float dot8(float4 a0, float4 a1, float4 b0, float4 b1) {
    return a0.x*b0.x + a0.y*b0.y + a0.z*b0.z + a0.w*b0.w
         + a1.x*b1.x + a1.y*b1.y + a1.z*b1.z + a1.w*b1.w;
}

// Fused prep + MLP. Grid: 1024 blocks x 256 threads; block covers 256 timesteps,
// each wave 4 MFMA tiles of 16. u written to ws, yd written to d_out.
__global__ __launch_bounds__(256) void mlp_kernel(
    const float* __restrict__ x, const float* __restrict__ W1,
    const float* __restrict__ b1, const float* __restrict__ W2,
    const float* __restrict__ b2, const float* __restrict__ Wu,
    const float* __restrict__ Dv, const float* __restrict__ b_y,
    float* __restrict__ u, float* __restrict__ yd)
{
    __shared__ __align__(16) uint4 fragLDS[4 * 64];      // 4 KB: W1 bf16 B-fragments
    __shared__ float pu[32 * 8], pd[32 * 8], pc[16];
    __shared__ float wuF[32], wdF[32], cucd[2];

    int tid = threadIdx.x;

    // --- per-block prep, phase A ---------------------------------------
    {   // W1 -> bf16 MFMA B-fragment. frag f = khalf + 2*ntile.
        // B[k][n] held by lane: n=(lane&15)+16*ntile, k=khalf*32+(lane>>4)*8+j
        int f    = tid >> 6;
        int lane = tid & 63;
        int khalf = f & 1, ntile = f >> 1;
        int quad  = lane >> 4;
        int nn    = (lane & 15) + ntile * 16;
        unsigned short h8[8];
#pragma unroll
        for (int j = 0; j < 8; ++j) {
            int k = khalf * 32 + quad * 8 + j;
            h8[j] = f2bf(W1[k * HIDN + nn]);
        }
        fragLDS[tid] = make_uint4(
            (unsigned int)h8[0] | ((unsigned int)h8[1] << 16),
            (unsigned int)h8[2] | ((unsigned int)h8[3] << 16),
            (unsigned int)h8[4] | ((unsigned int)h8[5] << 16),
            (unsigned int)h8[6] | ((unsigned int)h8[7] << 16));
    }
    {   // folded readouts, 8-way partials: h = tid>>3, part = tid&7
        int h = tid >> 3, part = tid & 7;
        const float4* w2p = (const float4*)(W2 + h * FFD + part * 8);
        float4 wa = w2p[0], wb = w2p[1];
        float4 ua = *(const float4*)(Wu + part * 8);
        float4 ub = *(const float4*)(Wu + part * 8 + 4);
        float4 da = *(const float4*)(Dv + part * 8);
        float4 db = *(const float4*)(Dv + part * 8 + 4);
        pu[tid] = dot8(wa, wb, ua, ub);
        pd[tid] = dot8(wa, wb, da, db);
        if (tid < 8) {          // cu partials
            float4 ba = *(const float4*)(b2 + tid * 8);
            float4 bb = *(const float4*)(b2 + tid * 8 + 4);
            float4 u2a = *(const float4*)(Wu + tid * 8);
            float4 u2b = *(const float4*)(Wu + tid * 8 + 4);
            pc[tid] = dot8(ba, bb, u2a, u2b);
        } else if (tid < 16) {  // cd partials
            int p = tid - 8;
            float4 ba = *(const float4*)(b2 + p * 8);
            float4 bb = *(const float4*)(b2 + p * 8 + 4);
            float4 d2a = *(const float4*)(Dv + p * 8);
            float4 d2b = *(const float4*)(Dv + p * 8 + 4);
            pc[tid] = dot8(ba, bb, d2a, d2b);
        }
    }
    __syncthreads();
    // --- phase B: finalize folds ---------------------------------------
    if (tid < 32) {
        float s = 0.f;
#pragma unroll
        for (int p = 0; p < 8; ++p) s += pu[tid * 8 + p];
        wuF[tid] = s;
    } else if (tid < 64) {
        int h = tid - 32;
        float s = 0.f;
#pragma unroll
        for (int p = 0; p < 8; ++p) s += pd[h * 8 + p];
        wdF[h] = s;
    } else if (tid == 64) {
        float s = 0.f;
#pragma unroll
        for (int p = 0; p < 8; ++p) s += pc[p];
        cucd[0] = s;
    } else if (tid == 65) {
        float s = 0.f;
#pragma unroll
        for (int p = 8; p < 16; ++p) s += pc[p];
        cucd[1] = s + b_y[0];
    }
    __syncthreads();

    // --- main: 4 tiles per wave ----------------------------------------
    int lane = tid & 63, wid = tid >> 6;
    int m = lane & 15, quad = lane >> 4;

    short8 bk0n0 = __builtin_bit_cast(short8, fragLDS[0 * 64 + lane]);
    short8 bk1n0 = __builtin_bit_cast(short8, fragLDS[1 * 64 + lane]);
    short8 bk0n1 = __builtin_bit_cast(short8, fragLDS[2 * 64 + lane]);
    short8 bk1n1 = __builtin_bit_cast(short8, fragLDS[3 * 64 + lane]);

    float b1n0 = b1[m],       b1n1 = b1[16 + m];
    float wu0  = wuF[m],      wu1  = wuF[16 + m];
    float wd0  = wdF[m],      wd1  = wdF[16 + m];
    float cu   = cucd[0],     cd   = cucd[1];

    int tbase = blockIdx.x * 256 + wid * 64;     // wave covers 64 timesteps
    const float* xr = x + (size_t)(tbase + m) * FIN + quad * 8;

    float4 xv[2][4];
#define LOADT(buf, tt) { const float* p_ = xr + (tt) * 16 * FIN;          \
        (buf)[0] = *(const float4*)(p_);      (buf)[1] = *(const float4*)(p_ + 4);  \
        (buf)[2] = *(const float4*)(p_ + 32); (buf)[3] = *(const float4*)(p_ + 36); }

    LOADT(xv[0], 0);
    LOADT(xv[1], 1);

#pragma unroll
    for (int tt = 0; tt < TPW; ++tt) {
        float4 x0 = xv[tt & 1][0], x1 = xv[tt & 1][1];
        float4 x2 = xv[tt & 1][2], x3 = xv[tt & 1][3];
        if (tt + 2 < TPW) LOADT(xv[tt & 1], tt + 2);

        short8 a0, a1;
        a0[0] = (short)f2bf(x0.x); a0[1] = (short)f2bf(x0.y);
        a0[2] = (short)f2bf(x0.z); a0[3] = (short)f2bf(x0.w);
        a0[4] = (short)f2bf(x1.x); a0[5] = (short)f2bf(x1.y);
        a0[6] = (short)f2bf(x1.z); a0[7] = (short)f2bf(x1.w);
        a1[0] = (short)f2bf(x2.x); a1[1] = (short)f2bf(x2.y);
        a1[2] = (short)f2bf(x2.z); a1[3] = (short)f2bf(x2.w);
        a1[4] = (short)f2bf(x3.x); a1[5] = (short)f2bf(x3.y);
        a1[6] = (short)f2bf(x3.z); a1[7] = (short)f2bf(x3.w);

        f32x4 acc0 = {0.f, 0.f, 0.f, 0.f};
        f32x4 acc1 = {0.f, 0.f, 0.f, 0.f};
        acc0 = __builtin_amdgcn_mfma_f32_16x16x32_bf16(a0, bk0n0, acc0, 0, 0, 0);
        acc0 = __builtin_amdgcn_mfma_f32_16x16x32_bf16(a1, bk1n0, acc0, 0, 0, 0);
        acc1 = __builtin_amdgcn_mfma_f32_16x16x32_bf16(a0, bk0n1, acc1, 0, 0, 0);
        acc1 = __builtin_amdgcn_mfma_f32_16x16x32_bf16(a1, bk1n1, acc1, 0, 0, 0);

        // C/D layout: col(n) = lane&15, row(t) = quad*4 + reg  [HW-verified]
        float ut[4], yt[4];
#pragma unroll
        for (int r = 0; r < 4; ++r) {
            float h0 = fmaxf(acc0[r] + b1n0, 0.f);
            float h1 = fmaxf(acc1[r] + b1n1, 0.f);
            ut[r] = h0 * wu0 + h1 * wu1;
            yt[r] = h0 * wd0 + h1 * wd1;
        }
#pragma unroll
        for (int mask = 1; mask <= 8; mask <<= 1) {
#pragma unroll
            for (int r = 0; r < 4; ++r) {
                ut[r] += __shfl_xor(ut[r], mask);
                yt[r] += __shfl_xor(yt[r], mask);
            }
        }
        if (m == 0) {
            int row = tbase + tt * 16 + quad * 4;
            *(float4*)&u[row]  = make_float4(ut[0] + cu, ut[1] + cu, ut[2] + cu, ut[3] + cu);
            *(float4*)&yd[row] = make_float4(yt[0] + cd, yt[1] + cd, yt[2] + cd, yt[3] + cd);
        }
    }
#undef LOADT
}

// Causal FIR: y[b,t] = yd[b,t] + sum_{j<WWIN} K[j]*u[b,t-j]; K computed in-block.
__global__ __launch_bounds__(256) void conv_kernel(
    const float* __restrict__ u, const float* __restrict__ Lraw,
    const float* __restrict__ P, const float* __restrict__ C,
    float* __restrict__ y)
{
    __shared__ __align__(16) float us[WWIN + TILE];
    __shared__ __align__(16) float Ks[WWIN];
    __shared__ float spv[NST], cpv[NST];

    int tid = threadIdx.x;
    const int blocksPerSeq = TT / TILE;               // 32
    int b  = blockIdx.x / blocksPerSeq;
    int t0 = (blockIdx.x % blocksPerSeq) * TILE;
    const float* ub = u + (size_t)b * TT;

    // stage u halo + tile
    for (int s = tid; s < WWIN + TILE; s += 256) {
        int gt = t0 - WWIN + s;
        us[s] = (gt >= 0) ? ub[gt] : 0.f;
    }
    // decay rates
    if (tid < NST) {
        float raw = Lraw[tid];
        spv[tid] = fmaxf(raw, 0.f) + log1pf(expf(-fabsf(raw)));  // stable softplus
        cpv[tid] = C[tid] * P[tid];
    }
    __syncthreads();
    // FIR taps: K[j] = sum_n cp[n] * exp(-sp[n]*j)
    {
        float jf = (float)tid;
        float acc = 0.f;
#pragma unroll 4
        for (int n = 0; n < NST; ++n) acc += cpv[n] * __expf(-spv[n] * jf);
        Ks[tid] = acc;
    }
    __syncthreads();

    int base = WWIN + tid * 4;
    size_t oidx = (size_t)b * TT + t0 + tid * 4;
    float4 yv = *(const float4*)&y[oidx];             // yd from mlp_kernel
    float a0 = yv.x, a1 = yv.y, a2 = yv.z, a3 = yv.w;

#pragma unroll 8
    for (int j = 0; j < WWIN; j += 4) {
        float4 kk = *(const float4*)&Ks[j];
        float4 ua = *(const float4*)&us[base - j - 4];
        float4 ux = *(const float4*)&us[base - j];
        a0 += kk.x * ux.x + kk.y * ua.w + kk.z * ua.z + kk.w * ua.y;
        a1 += kk.x * ux.y + kk.y * ux.x + kk.z * ua.w + kk.w * ua.z;
        a2 += kk.x * ux.z + kk.y * ux.y + kk.z * ux.x + kk.w * ua.w;
        a3 += kk.x * ux.w + kk.y * ux.z + kk.z * ux.y + kk.w * ux.x;
    }
    *(float4*)&y[oidx] = make_float4(a0, a1, a2, a3);
}

extern "C" void kernel_launch(void* const* d_in, const int* in_sizes, int n_in,
                              void* d_out, int out_size, void* d_ws, size_t ws_size,
                              hipStream_t stream)
{
    const float* x    = (const float*)d_in[0];
    const float* W1   = (const float*)d_in[1];
    const float* b1   = (const float*)d_in[2];
    const float* W2   = (const float*)d_in[3];
    const float* b2   = (const float*)d_in[4];
    const float* Lraw = (const float*)d_in[5];
    const float* P    = (const float*)d_in[6];
    const float* Wu   = (const float*)d_in[7];
    const float* C    = (const float*)d_in[8];
    const float* Dv   = (const float*)d_in[9];
    const float* b_y  = (const float*)d_in[10];

    float* u = (float*)d_ws;       // B*T floats = 1 MB of ws
    float* y = (float*)d_out;

    mlp_kernel<<<(BB * TT) / 256, 256, 0, stream>>>(x, W1, b1, W2, b2, Wu, Dv, b_y, u, y);
    conv_kernel<<<(BB * TT) / TILE, 256, 0, stream>>>(u, Lraw, P, C, y);
}

// Round 4
// 122.279 us; speedup vs baseline: 1.2544x; 1.0095x over previous
//
#include <hip/hip_runtime.h>
#include <hip/hip_bf16.h>

// Problem constants: B=8, T=32768, F_IN=64, N=64, F=64, HID=32
#define BB   8
#define TT   32768
#define FIN  64
#define HIDN 32
#define NST  64
#define FFD  64
#define WWIN 256        // FIR window: A^256 ~ 1e-45 -> exact truncation in fp32
#define TILE 1024       // conv outputs per block
#define TPW  4          // MFMA tiles (of 16 timesteps) per wave in mlp

typedef __attribute__((ext_vector_type(8))) short short8;
typedef __attribute__((ext_vector_type(4))) float f32x4;

static __device__ __forceinline__ unsigned short f2bf(float f) {
    unsigned int u = __builtin_bit_cast(unsigned int, f);
    unsigned int lsb = (u >> 16) & 1u;
    u += 0x7fffu + lsb;                 // round-to-nearest-even
    return (unsigned short)(u >> 16);
}

static __device__ __forceinline__ float dot8(float4 a0, float4 a1, float4 b0, float4 b1) {
    return a0.x*b0.x + a0.y*b0.y + a0.z*b0.z + a0.w*b0.w
         + a1.x*b1.x + a1.y*b1.y + a1.z*b1.z + a1.w*b1.w;
}

// Pack 8 fp32 -> short8 of bf16 via v_cvt_pk_bf16_f32 (RNE, matches f2bf bitwise)
static __device__ __forceinline__ short8 pack_bf8(float4 a, float4 b) {
    union { short8 s8; __hip_bfloat162 b2[4]; } u;
    u.b2[0] = __float22bfloat162_rn({a.x, a.y});
    u.b2[1] = __float22bfloat162_rn({a.z, a.w});
    u.b2[2] = __float22bfloat162_rn({b.x, b.y});
    u.b2[3] = __float22bfloat162_rn({b.z, b.w});
    return u.s8;
}

// Fused prep + MLP. Grid: 1024 blocks x 256 threads; block covers 256 timesteps,
// each wave 4 MFMA tiles of 16. u -> ws, yd -> d_out.
// MFMA operand order: D = W1frag * xfrag, so C/D holds D[n=quad*4+r][t=lane&15].
__global__ __launch_bounds__(256) void mlp_kernel(
    const float* __restrict__ x, const float* __restrict__ W1,
    const float* __restrict__ b1, const float* __restrict__ W2,
    const float* __restrict__ b2, const float* __restrict__ Wu,
    const float* __restrict__ Dv, const float* __restrict__ b_y,
    float* __restrict__ u, float* __restrict__ yd)
{
    __shared__ __align__(16) uint4 fragLDS[4 * 64];      // 4 KB: W1 bf16 fragments
    __shared__ float pu[32 * 8], pd[32 * 8], pc[16];
    __shared__ __align__(16) float wuF[32], wdF[32];
    __shared__ float cucd[2];

    int tid = threadIdx.x;

    // --- per-block prep, phase A ---------------------------------------
    {   // W1 -> bf16 fragment. frag f = khalf + 2*ntile.
        // lane holds W1[k][n] with n=(lane&15)+16*ntile, k=khalf*32+(lane>>4)*8+j
        int f    = tid >> 6;
        int lane = tid & 63;
        int khalf = f & 1, ntile = f >> 1;
        int quad  = lane >> 4;
        int nn    = (lane & 15) + ntile * 16;
        unsigned short h8[8];
#pragma unroll
        for (int j = 0; j < 8; ++j) {
            int k = khalf * 32 + quad * 8 + j;
            h8[j] = f2bf(W1[k * HIDN + nn]);
        }
        fragLDS[tid] = make_uint4(
            (unsigned int)h8[0] | ((unsigned int)h8[1] << 16),
            (unsigned int)h8[2] | ((unsigned int)h8[3] << 16),
            (unsigned int)h8[4] | ((unsigned int)h8[5] << 16),
            (unsigned int)h8[6] | ((unsigned int)h8[7] << 16));
    }
    {   // folded readouts, 8-way partials: h = tid>>3, part = tid&7
        int h = tid >> 3, part = tid & 7;
        const float4* w2p = (const float4*)(W2 + h * FFD + part * 8);
        float4 wa = w2p[0], wb = w2p[1];
        float4 ua = *(const float4*)(Wu + part * 8);
        float4 ub = *(const float4*)(Wu + part * 8 + 4);
        float4 da = *(const float4*)(Dv + part * 8);
        float4 db = *(const float4*)(Dv + part * 8 + 4);
        pu[tid] = dot8(wa, wb, ua, ub);
        pd[tid] = dot8(wa, wb, da, db);
        if (tid < 8) {
            float4 ba = *(const float4*)(b2 + tid * 8);
            float4 bb = *(const float4*)(b2 + tid * 8 + 4);
            float4 u2a = *(const float4*)(Wu + tid * 8);
            float4 u2b = *(const float4*)(Wu + tid * 8 + 4);
            pc[tid] = dot8(ba, bb, u2a, u2b);
        } else if (tid < 16) {
            int p = tid - 8;
            float4 ba = *(const float4*)(b2 + p * 8);
            float4 bb = *(const float4*)(b2 + p * 8 + 4);
            float4 d2a = *(const float4*)(Dv + p * 8);
            float4 d2b = *(const float4*)(Dv + p * 8 + 4);
            pc[tid] = dot8(ba, bb, d2a, d2b);
        }
    }
    __syncthreads();
    // --- phase B: finalize folds ---------------------------------------
    if (tid < 32) {
        float s = 0.f;
#pragma unroll
        for (int p = 0; p < 8; ++p) s += pu[tid * 8 + p];
        wuF[tid] = s;
    } else if (tid < 64) {
        int h = tid - 32;
        float s = 0.f;
#pragma unroll
        for (int p = 0; p < 8; ++p) s += pd[h * 8 + p];
        wdF[h] = s;
    } else if (tid == 64) {
        float s = 0.f;
#pragma unroll
        for (int p = 0; p < 8; ++p) s += pc[p];
        cucd[0] = s;
    } else if (tid == 65) {
        float s = 0.f;
#pragma unroll
        for (int p = 8; p < 16; ++p) s += pc[p];
        cucd[1] = s + b_y[0];
    }
    __syncthreads();

    // --- main: 4 tiles per wave ----------------------------------------
    int lane = tid & 63, wid = tid >> 6;
    int m = lane & 15, quad = lane >> 4;

    short8 bk0n0 = __builtin_bit_cast(short8, fragLDS[0 * 64 + lane]);
    short8 bk1n0 = __builtin_bit_cast(short8, fragLDS[1 * 64 + lane]);
    short8 bk0n1 = __builtin_bit_cast(short8, fragLDS[2 * 64 + lane]);
    short8 bk1n1 = __builtin_bit_cast(short8, fragLDS[3 * 64 + lane]);

    // per-lane readout constants, indexed by n = quad*4 + r (and +16)
    float4 b1A = *(const float4*)&b1[quad * 4];
    float4 b1B = *(const float4*)&b1[16 + quad * 4];
    float4 wuA = *(const float4*)&wuF[quad * 4];
    float4 wuB = *(const float4*)&wuF[16 + quad * 4];
    float4 wdA = *(const float4*)&wdF[quad * 4];
    float4 wdB = *(const float4*)&wdF[16 + quad * 4];
    float cu = cucd[0], cd = cucd[1];

    int tbase = blockIdx.x * 256 + wid * 64;     // wave covers 64 timesteps
    const float* xr = x + (size_t)(tbase + m) * FIN + quad * 8;

    float4 xv[2][4];
#define LOADT(buf, tt) { const float* p_ = xr + (tt) * 16 * FIN;          \
        (buf)[0] = *(const float4*)(p_);      (buf)[1] = *(const float4*)(p_ + 4);  \
        (buf)[2] = *(const float4*)(p_ + 32); (buf)[3] = *(const float4*)(p_ + 36); }

    LOADT(xv[0], 0);
    LOADT(xv[1], 1);

#pragma unroll
    for (int tt = 0; tt < TPW; ++tt) {
        float4 x0 = xv[tt & 1][0], x1 = xv[tt & 1][1];
        float4 x2 = xv[tt & 1][2], x3 = xv[tt & 1][3];
        if (tt + 2 < TPW) LOADT(xv[tt & 1], tt + 2);

        short8 a0 = pack_bf8(x0, x1);   // x[t][k], khalf 0
        short8 a1 = pack_bf8(x2, x3);   // khalf 1

        f32x4 acc0 = {0.f, 0.f, 0.f, 0.f};
        f32x4 acc1 = {0.f, 0.f, 0.f, 0.f};
        // D = W1^T-frag (as A) * x-frag (as B): D[n][t], n=quad*4+r, t=lane&15
        acc0 = __builtin_amdgcn_mfma_f32_16x16x32_bf16(bk0n0, a0, acc0, 0, 0, 0);
        acc0 = __builtin_amdgcn_mfma_f32_16x16x32_bf16(bk1n0, a1, acc0, 0, 0, 0);
        acc1 = __builtin_amdgcn_mfma_f32_16x16x32_bf16(bk0n1, a0, acc1, 0, 0, 0);
        acc1 = __builtin_amdgcn_mfma_f32_16x16x32_bf16(bk1n1, a1, acc1, 0, 0, 0);

        float ut = 0.f, yt = 0.f, h;
        h = fmaxf(acc0[0] + b1A.x, 0.f); ut += h * wuA.x; yt += h * wdA.x;
        h = fmaxf(acc0[1] + b1A.y, 0.f); ut += h * wuA.y; yt += h * wdA.y;
        h = fmaxf(acc0[2] + b1A.z, 0.f); ut += h * wuA.z; yt += h * wdA.z;
        h = fmaxf(acc0[3] + b1A.w, 0.f); ut += h * wuA.w; yt += h * wdA.w;
        h = fmaxf(acc1[0] + b1B.x, 0.f); ut += h * wuB.x; yt += h * wdB.x;
        h = fmaxf(acc1[1] + b1B.y, 0.f); ut += h * wuB.y; yt += h * wdB.y;
        h = fmaxf(acc1[2] + b1B.z, 0.f); ut += h * wuB.z; yt += h * wdB.z;
        h = fmaxf(acc1[3] + b1B.w, 0.f); ut += h * wuB.w; yt += h * wdB.w;

        // reduce over the 4 quad-groups (n blocks of 4): 2-level tree
        ut += __shfl_xor(ut, 16); ut += __shfl_xor(ut, 32);
        yt += __shfl_xor(yt, 16); yt += __shfl_xor(yt, 32);

        if (lane < 16) {                 // quad==0 holds full sums; t = lane
            int row = tbase + tt * 16 + lane;
            u[row]  = ut + cu;
            yd[row] = yt + cd;
        }
    }
#undef LOADT
}

// Causal FIR: y[b,t] = yd[b,t] + sum_{j<WWIN} K[j]*u[b,t-j]; K computed in-block.
__global__ __launch_bounds__(256) void conv_kernel(
    const float* __restrict__ u, const float* __restrict__ Lraw,
    const float* __restrict__ P, const float* __restrict__ C,
    float* __restrict__ y)
{
    __shared__ __align__(16) float us[WWIN + TILE];
    __shared__ __align__(16) float Ks[WWIN];
    __shared__ float spv[NST], cpv[NST];

    int tid = threadIdx.x;
    const int blocksPerSeq = TT / TILE;               // 32
    int b  = blockIdx.x / blocksPerSeq;
    int t0 = (blockIdx.x % blocksPerSeq) * TILE;
    const float* ub = u + (size_t)b * TT;

    for (int s = tid; s < WWIN + TILE; s += 256) {
        int gt = t0 - WWIN + s;
        us[s] = (gt >= 0) ? ub[gt] : 0.f;
    }
    if (tid < NST) {
        float raw = Lraw[tid];
        spv[tid] = fmaxf(raw, 0.f) + log1pf(expf(-fabsf(raw)));  // stable softplus
        cpv[tid] = C[tid] * P[tid];
    }
    __syncthreads();
    {   // FIR taps: K[j] = sum_n cp[n] * exp(-sp[n]*j)
        float jf = (float)tid;
        float acc = 0.f;
#pragma unroll 4
        for (int n = 0; n < NST; ++n) acc += cpv[n] * __expf(-spv[n] * jf);
        Ks[tid] = acc;
    }
    __syncthreads();

    int base = WWIN + tid * 4;
    size_t oidx = (size_t)b * TT + t0 + tid * 4;
    float4 yv = *(const float4*)&y[oidx];             // yd from mlp_kernel
    float a0 = yv.x, a1 = yv.y, a2 = yv.z, a3 = yv.w;

#pragma unroll 8
    for (int j = 0; j < WWIN; j += 4) {
        float4 kk = *(const float4*)&Ks[j];
        float4 ua = *(const float4*)&us[base - j - 4];
        float4 ux = *(const float4*)&us[base - j];
        a0 += kk.x * ux.x + kk.y * ua.w + kk.z * ua.z + kk.w * ua.y;
        a1 += kk.x * ux.y + kk.y * ux.x + kk.z * ua.w + kk.w * ua.z;
        a2 += kk.x * ux.z + kk.y * ux.y + kk.z * ux.x + kk.w * ua.w;
        a3 += kk.x * ux.w + kk.y * ux.z + kk.z * ux.y + kk.w * ux.x;
    }
    *(float4*)&y[oidx] = make_float4(a0, a1, a2, a3);
}

extern "C" void kernel_launch(void* const* d_in, const int* in_sizes, int n_in,
                              void* d_out, int out_size, void* d_ws, size_t ws_size,
                              hipStream_t stream)
{
    const float* x    = (const float*)d_in[0];
    const float* W1   = (const float*)d_in[1];
    const float* b1   = (const float*)d_in[2];
    const float* W2   = (const float*)d_in[3];
    const float* b2   = (const float*)d_in[4];
    const float* Lraw = (const float*)d_in[5];
    const float* P    = (const float*)d_in[6];
    const float* Wu   = (const float*)d_in[7];
    const float* C    = (const float*)d_in[8];
    const float* Dv   = (const float*)d_in[9];
    const float* b_y  = (const float*)d_in[10];

    float* u = (float*)d_ws;       // B*T floats = 1 MB of ws
    float* y = (float*)d_out;

    mlp_kernel<<<(BB * TT) / 256, 256, 0, stream>>>(x, W1, b1, W2, b2, Wu, Dv, b_y, u, y);
    conv_kernel<<<(BB * TT) / TILE, 256, 0, stream>>>(u, Lraw, P, C, y);
}